// Round 7
// baseline (211.200 us; speedup 1.0000x reference)
//
#include <hip/hip_runtime.h>
#include <hip/hip_bf16.h>

// PointNet2Refine fused: [K0] pack (coalesced, 16x16 frag maps) + xyzw table
// -> [K1] fused ballq + transform + MFMA MLP, TWO bn rows per block (p=128).
// B=2, NUM=512, A=20000, Bn=1024.

#define A_PTS   20000
#define BN_TOT  1024
#define NNEI    192
#define GNUM    64
#define R2      0.09f
#define CHUNKS  313   // ceil(20000/64)
#define PDIM    128   // 2 rows x 64 gripper slots

typedef __attribute__((ext_vector_type(8))) short bf16x8;
typedef __attribute__((ext_vector_type(4))) float f32x4;

__device__ inline unsigned short f2bf(float v) {
    __hip_bfloat16 h = __float2bfloat16(v);
    return *reinterpret_cast<unsigned short*>(&h);
}

// ---------------- K0: pack weights (coalesced) + xyzw table -----------------
// 16x16 frag contract (round-5, proven):
//   dst[((ot*KS+ks)*64+l)*8+e] = W[ot*16+(l&15)][ks*32+(l>>4)*8+e]
// Same k-map used on the LDS B-read side, so any k-map error cancels.
#define P_W2_END 32768            // 256 o * 128 k4
#define P_W3_END 49152            // + 256 o * 64 k4
#define P_W4_END 57344            // + 128 o * 64 k4
#define P_HP_END 59392            // + 2048 elementwise
#define P_W1_END 75776            // + 32 ot * 512 elementwise (W1 + b1 at k=3)
#define P_XW_END 115776           // + 40000 points
__global__ __launch_bounds__(256) void k_pack(
    const float* __restrict__ W1, const float* __restrict__ b1,
    const float* __restrict__ W2, const float* __restrict__ W3,
    const float* __restrict__ W4,
    const float* __restrict__ regw, const float* __restrict__ clsw,
    const float* __restrict__ pc,
    unsigned short* __restrict__ W2p, unsigned short* __restrict__ W3p,
    unsigned short* __restrict__ W4p, unsigned short* __restrict__ Hp,
    unsigned short* __restrict__ W1p, float4* __restrict__ xyzw)
{
    int t = blockIdx.x * 256 + threadIdx.x;
    if (t < P_W2_END) {
        int o = t >> 7, k = (t & 127) << 2;          // o in [0,256), k in [0,512)
        float4 v = *reinterpret_cast<const float4*>(W2 + o*512 + k);
        int ot=o>>4, lp=o&15, ks=k>>5, kg=(k>>3)&3, e0=k&7;
        int d = ((ot*16 + ks)*64 + kg*16 + lp)*8 + e0;
        *reinterpret_cast<ushort4*>(W2p + d) =
            make_ushort4(f2bf(v.x), f2bf(v.y), f2bf(v.z), f2bf(v.w));
    } else if (t < P_W3_END) {
        int i = t - P_W2_END;
        int o = i >> 6, k = (i & 63) << 2;           // o in [0,256), k in [0,256)
        float4 v = *reinterpret_cast<const float4*>(W3 + o*256 + k);
        int ot=o>>4, lp=o&15, ks=k>>5, kg=(k>>3)&3, e0=k&7;
        int d = ((ot*8 + ks)*64 + kg*16 + lp)*8 + e0;
        *reinterpret_cast<ushort4*>(W3p + d) =
            make_ushort4(f2bf(v.x), f2bf(v.y), f2bf(v.z), f2bf(v.w));
    } else if (t < P_W4_END) {
        int i = t - P_W3_END;
        int o = i >> 6, k = (i & 63) << 2;           // o in [0,128), k in [0,256)
        float4 v = *reinterpret_cast<const float4*>(W4 + o*256 + k);
        int ot=o>>4, lp=o&15, ks=k>>5, kg=(k>>3)&3, e0=k&7;
        int d = ((ot*8 + ks)*64 + kg*16 + lp)*8 + e0;
        *reinterpret_cast<ushort4*>(W4p + d) =
            make_ushort4(f2bf(v.x), f2bf(v.y), f2bf(v.z), f2bf(v.w));
    } else if (t < P_HP_END) {
        int i2 = t - P_W4_END;
        int ks = i2 >> 9, r = i2 & 511, l = r >> 3, e = r & 7;
        int c = l & 15;
        int k = 256 + ks*32 + ((l >> 4) << 3) + e;
        float v = 0.f;
        if (c < 8)       v = regw[c*384 + k];
        else if (c < 10) v = clsw[(c-8)*384 + k];
        Hp[i2] = f2bf(v);
    } else if (t < P_W1_END) {
        int i = t - P_HP_END;
        int ot = i >> 9, r = i & 511, l = r >> 3, e = r & 7;
        int o = ot*16 + (l & 15);
        int k = ((l >> 4) << 3) + e;
        float v = (k < 3) ? W1[o*3 + k] : (k == 3 ? b1[o] : 0.f);
        W1p[i] = f2bf(v);
    } else if (t < P_XW_END) {
        int i = t - P_W1_END;
        int b = (i >= A_PTS) ? 1 : 0;
        int a = i - b * A_PTS;
        const float* pp = pc + b*(A_PTS*6) + a*6;
        float x = pp[0], y = pp[1], z = pp[2];
        xyzw[i] = make_float4(x, y, z, x*x + y*y + z*z);
    }
}

// ---------------- K1: fused ballq + transform + MLP, 2 rows per block -------
// 512 thr = 8 waves. Rows r=0,1 (bn0, bn0+1). B/T scratch overlaid on bufA
// (dead before first bufA write; h=0 barrier guards gp reads vs writes).
__global__ __launch_bounds__(512, 2) void k_fused(
    const float* __restrict__ grasp, const float4* __restrict__ xyzw,
    const float* __restrict__ s1,
    const float* __restrict__ b2, const float* __restrict__ b3,
    const float* __restrict__ b4,
    const unsigned short* __restrict__ W2p, const unsigned short* __restrict__ W3p,
    const unsigned short* __restrict__ W4p, const unsigned short* __restrict__ Hp,
    const unsigned short* __restrict__ W1p,
    const float* __restrict__ regw, const float* __restrict__ regb,
    const float* __restrict__ clsw, const float* __restrict__ clsb,
    const float* __restrict__ dcrw, const float* __restrict__ dcrb,
    const float* __restrict__ dccw, const float* __restrict__ dccb,
    float* __restrict__ outp)
{
    __shared__ __align__(16) unsigned short bufA[32*PDIM*8];  // 64 KiB
    __shared__ __align__(16) unsigned short bufB[32*PDIM*8];  // 64 KiB
    __shared__ float sdot[2][16];
    __shared__ float pdc[8][16];

    // ---- overlay scratch inside bufA (byte offsets, all aligned) ----
    char* sb = (char*)bufA;
    float4* tval              = (float4*)sb;                       // [2][192] @0
    float4* gp                = (float4*)(sb + 6144);              // [2][64]
    unsigned long long* masks = (unsigned long long*)(sb + 8192);  // [2][313]
    int* soff                 = (int*)(sb + 13200);                // [2][313]
    int* idxs                 = (int*)(sb + 15704);                // [2][192]
    unsigned long long* tmask = (unsigned long long*)(sb + 17240); // [2][3]
    int* sh_tot               = (int*)(sb + 17288);                // [2]
    int* sh_padv              = (int*)(sb + 17296);                // [2]

    int bn0  = blockIdx.x * 2;
    int tid  = threadIdx.x;
    int lane = tid & 63;
    int w    = tid >> 6;      // 0..7

    const float* gr0 = grasp + bn0 * 8;
    const float* gr1 = grasp + (bn0 + 1) * 8;
    float A0=gr0[0],A1=gr0[1],A2=gr0[2],A3=gr0[3],A4=gr0[4],A5=gr0[5],A6=gr0[6],A7=gr0[7];
    float B0=gr1[0],B1=gr1[1],B2=gr1[2],B3=gr1[3],B4=gr1[4],B5=gr1[5],B6=gr1[6],B7=gr1[7];
    const float4* xw = xyzw + (bn0 >> 9) * A_PTS;

    // ================= Phase B: ball query (both rows, one stream) =========
    float cc0 = A0*A0 + A1*A1 + A2*A2;
    float cc1 = B0*B0 + B1*B1 + B2*B2;
    for (int c = w; c < CHUNKS; c += 8) {
        int a = c * 64 + lane;
        bool v0 = false, v1 = false;
        if (a < A_PTS) {
            float4 q = xw[a];
            float d0 = cc0 + q.w - 2.0f * (A0*q.x + A1*q.y + A2*q.z);
            float d1 = cc1 + q.w - 2.0f * (B0*q.x + B1*q.y + B2*q.z);
            v0 = d0 < R2; v1 = d1 < R2;
        }
        unsigned long long m0 = __ballot(v0);
        unsigned long long m1 = __ballot(v1);
        if (lane == 0) { masks[c] = m0; masks[CHUNKS + c] = m1; }
    }
    __syncthreads();

    if (w < 2) {   // wave w scans row w's chunk popcounts (ordered)
        const unsigned long long* mrow = masks + w * CHUNKS;
        int* srow = soff + w * CHUNKS;
        int c0 = lane * 5;
        int cnts[5]; int s = 0;
        #pragma unroll
        for (int i = 0; i < 5; ++i) {
            int c = c0 + i;
            int v = (c < CHUNKS) ? __popcll(mrow[c]) : 0;
            cnts[i] = v; s += v;
        }
        int incl = s;
        for (int o2 = 1; o2 < 64; o2 <<= 1) {
            int v = __shfl_up(incl, o2, 64);
            if (lane >= o2) incl += v;
        }
        int run = incl - s;
        #pragma unroll
        for (int i = 0; i < 5; ++i) {
            int c = c0 + i;
            if (c < CHUNKS) srow[c] = run;
            run += cnts[i];
        }
        int total = __shfl(incl, 63, 64);
        int fc = 0x7fffffff;
        #pragma unroll
        for (int i = 0; i < 5; ++i) {
            int c = c0 + i;
            if (c < CHUNKS && mrow[c] != 0ull) { fc = c; break; }
        }
        for (int o2 = 32; o2 >= 1; o2 >>= 1) fc = min(fc, __shfl_xor(fc, o2, 64));
        if (lane == 0) {
            sh_tot[w] = total;
            sh_padv[w] = (fc == 0x7fffffff) ? 0
                         : fc * 64 + (int)__builtin_ctzll(mrow[fc]);
        }
    }
    __syncthreads();

    {   // emit: waves 0-3 row0, waves 4-7 row1
        int re = w >> 2;
        const unsigned long long* mrow = masks + re * CHUNKS;
        const int* srow = soff + re * CHUNKS;
        int* irow = idxs + re * NNEI;
        for (int c = (w & 3); c < CHUNKS; c += 4) {
            unsigned long long mb = mrow[c];
            int base = srow[c];
            if (mb != 0ull && base < NNEI && ((mb >> lane) & 1ull)) {
                int pos = base + __popcll(mb & ((1ull << lane) - 1ull));
                if (pos < NNEI) irow[pos] = c * 64 + lane;
            }
        }
    }
    {   // pad idx: half-block per row
        int r = tid >> 8, tidr = tid & 255;
        int cnt = min(sh_tot[r], NNEI);
        for (int p = cnt + tidr; p < NNEI; p += 256) idxs[r*NNEI + p] = sh_padv[r];
    }
    __syncthreads();

    // ================= Phase T: gripper transform (half-block per row) =====
    int r    = tid >> 8;
    int tidr = tid & 255;
    float G0 = r ? B0 : A0, G1 = r ? B1 : A1, G2 = r ? B2 : A2, G3 = r ? B3 : A3;
    float G4 = r ? B4 : A4, G5 = r ? B5 : A5, G6 = r ? B6 : A6, G7 = r ? B7 : A7;
    float gsum = G0+G1+G2+G3+G4+G5+G6+G7;
    bool gmask = (gsum != -8.0f);
    float cx=G0, cy=G1, cz=G2;
    float ay0=G3, ay1=G4, ay2=G5;
    float cth = cosf(G6), sth = sinf(G6);
    float ny = sqrtf(ay0*ay0 + ay1*ay1 + ay2*ay2) + 1e-12f;
    ay0/=ny; ay1/=ny; ay2/=ny;
    float ax0=ay1, ax1=-ay0;
    float nx = sqrtf(ax0*ax0 + ax1*ax1) + 1e-12f;
    ax0/=nx; ax1/=nx;
    float az0 =  ax1*ay2;
    float az1 = -ax0*ay2;
    float az2 =  ax0*ay1 - ax1*ay0;
    float nz = sqrtf(az0*az0 + az1*az1 + az2*az2);
    if (nz == 0.0f) { az0=0.f; az1=0.f; az2=1.f; }
    else            { az0/=nz; az1/=nz; az2/=nz; }
    float ap0 = ax0*cth + az0*sth;
    float ap1 = ax1*cth + az1*sth;
    float ap2 =           az2*sth;
    float na = sqrtf(ap0*ap0 + ap1*ap1 + ap2*ap2) + 1e-12f;
    ap0/=na; ap1/=na; ap2/=na;
    float mi0 = ap1*ay2 - ap2*ay1;
    float mi1 = ap2*ay0 - ap0*ay2;
    float mi2 = ap0*ay1 - ap1*ay0;

    bool inside = false;
    if (tidr < NNEI) {
        float4 Q = xw[idxs[r*NNEI + tidr]];
        float qx = Q.x-cx, qy = Q.y-cy, qz = Q.z-cz;
        float tx = ap0*qx + ap1*qy + ap2*qz;
        float ty = ay0*qx + ay1*qy + ay2*qz;
        float tz = mi0*qx + mi1*qy + mi2*qz;
        inside = (tx > 0.f) && (tx < 0.3f) && (ty > -0.15f) && (ty < 0.15f)
              && (tz > -0.1f) && (tz < 0.1f);
        tval[r*NNEI + tidr] = make_float4(tx, ty, tz, 0.f);
    }
    unsigned long long mb = __ballot(inside);
    int wq = (tid >> 6) & 3;
    if (lane == 0 && wq < 3) tmask[r*3 + wq] = mb;
    __syncthreads();

    unsigned long long m0 = tmask[r*3+0], m1 = tmask[r*3+1], m2 = tmask[r*3+2];
    int c0 = __popcll(m0), c1 = __popcll(m1), c2 = __popcll(m2);
    int tfound = c0 + c1 + c2;
    int firstj = 0;
    if (m0)      firstj = (int)__builtin_ctzll(m0);
    else if (m1) firstj = 64 + (int)__builtin_ctzll(m1);
    else if (m2) firstj = 128 + (int)__builtin_ctzll(m2);
    float4 padv = tval[r*NNEI + firstj];

    if (tidr < NNEI && inside) {
        int wbase = (wq == 0) ? 0 : (wq == 1 ? c0 : c0 + c1);
        int rank = wbase + __popcll(mb & ((1ull << lane) - 1ull));
        if (rank < GNUM) gp[r*GNUM + rank] = tval[r*NNEI + tidr];
    }
    int gcnt = tfound < GNUM ? tfound : GNUM;
    for (int p = gcnt + tidr; p < GNUM; p += 256) gp[r*GNUM + p] = padv;
    if (tidr == 0)
        outp[10240 + bn0 + r] = (sh_tot[r] > 0 && tfound > 0 && gmask) ? 1.0f : 0.0f;
    __syncthreads();

    // ================= Phase M: MFMA MLP + heads (p = 128) =================
    int kg = lane >> 4;     // 0..3
    int lp = lane & 15;

    const bf16x8* pA  = reinterpret_cast<const bf16x8*>(bufA);
    const bf16x8* pB  = reinterpret_cast<const bf16x8*>(bufB);
    const bf16x8* w1f = reinterpret_cast<const bf16x8*>(W1p);
    const bf16x8* w2f = reinterpret_cast<const bf16x8*>(W2p);
    const bf16x8* w3f = reinterpret_cast<const bf16x8*>(W3p);
    const bf16x8* w4f = reinterpret_cast<const bf16x8*>(W4p);
    const bf16x8* hpf = reinterpret_cast<const bf16x8*>(Hp);

    // B-frags for L1: coords at assumed-k {0,1,2}, 1.0 at k=3 (bias row).
    // gp is flat [128] float4 (2 rows x 64). Read BEFORE first bufA write;
    // the h=0 __syncthreads below is the guard.
    bf16x8 bfr[8];
    #pragma unroll
    for (int pt = 0; pt < 8; ++pt) {
        float4 Pp = gp[pt*16 + lp];
        bf16x8 b = (bf16x8)(short)0;
        if (kg == 0) {
            b[0] = (short)f2bf(Pp.x);
            b[1] = (short)f2bf(Pp.y);
            b[2] = (short)f2bf(Pp.z);
            b[3] = (short)0x3F80;      // bf16(1.0)
        }
        bfr[pt] = b;
    }

    // ---- L1 (16x16, K-padded 3+bias) + L2 (K=512 in two 256 halves) ----
    f32x4 acc2[2][8];
    #pragma unroll
    for (int a = 0; a < 2; ++a)
        #pragma unroll
        for (int p = 0; p < 8; ++p) acc2[a][p] = (f32x4)0.f;

    for (int h = 0; h < 2; ++h) {
        __syncthreads();
        // L1: wave w computes global o-tiles(16) h*16 + {2w, 2w+1}
        f32x4 accL[2][8];
        #pragma unroll
        for (int a = 0; a < 2; ++a)
            #pragma unroll
            for (int p = 0; p < 8; ++p) accL[a][p] = (f32x4)0.f;
        {
            bf16x8 a0 = w1f[(h*16 + 2*w    )*64 + lane];
            bf16x8 a1 = w1f[(h*16 + 2*w + 1)*64 + lane];
            __builtin_amdgcn_s_setprio(1);
            #pragma unroll
            for (int pt = 0; pt < 8; ++pt) {
                accL[0][pt] = __builtin_amdgcn_mfma_f32_16x16x32_bf16(a0, bfr[pt], accL[0][pt], 0, 0, 0);
                accL[1][pt] = __builtin_amdgcn_mfma_f32_16x16x32_bf16(a1, bfr[pt], accL[1][pt], 0, 0, 0);
            }
            __builtin_amdgcn_s_setprio(0);
        }
        // L1 epilogue: relu -> bufA (local channels (2w+a)*16 + kg*4 .. +3)
        #pragma unroll
        for (int a = 0; a < 2; ++a) {
            int o0 = (2*w + a)*16 + kg*4;
            #pragma unroll
            for (int pt = 0; pt < 8; ++pt) {
                f32x4 d = accL[a][pt];
                int p = pt*16 + lp;
                uint2 q;
                q.x = (unsigned int)f2bf(fmaxf(d.x, 0.f)) |
                      ((unsigned int)f2bf(fmaxf(d.y, 0.f)) << 16);
                q.y = (unsigned int)f2bf(fmaxf(d.z, 0.f)) |
                      ((unsigned int)f2bf(fmaxf(d.w, 0.f)) << 16);
                *reinterpret_cast<uint2*>(&bufA[((o0 >> 3)*PDIM + p)*8 + (o0 & 7)]) = q;
            }
        }
        __syncthreads();
        // L2 accumulate over this half's 256 k-channels
        for (int ks = 0; ks < 8; ++ks) {
            int ksg = h*8 + ks;
            bf16x8 a0 = w2f[((2*w  )*16 + ksg)*64 + lane];
            bf16x8 a1 = w2f[((2*w+1)*16 + ksg)*64 + lane];
            __builtin_amdgcn_s_setprio(1);
            #pragma unroll
            for (int pt = 0; pt < 8; ++pt) {
                bf16x8 b = pA[(ks*4 + kg)*PDIM + pt*16 + lp];
                acc2[0][pt] = __builtin_amdgcn_mfma_f32_16x16x32_bf16(a0, b, acc2[0][pt], 0, 0, 0);
                acc2[1][pt] = __builtin_amdgcn_mfma_f32_16x16x32_bf16(a1, b, acc2[1][pt], 0, 0, 0);
            }
            __builtin_amdgcn_s_setprio(0);
        }
    }
    #pragma unroll
    for (int a = 0; a < 2; ++a) {
        int ot = 2*w + a;
        float4 bv = *reinterpret_cast<const float4*>(b2 + ot*16 + kg*4);
        int o0 = ot*16 + kg*4;
        #pragma unroll
        for (int pt = 0; pt < 8; ++pt) {
            f32x4 d = acc2[a][pt];
            int p = pt*16 + lp;
            uint2 q;
            q.x = (unsigned int)f2bf(fmaxf(d.x + bv.x, 0.f)) |
                  ((unsigned int)f2bf(fmaxf(d.y + bv.y, 0.f)) << 16);
            q.y = (unsigned int)f2bf(fmaxf(d.z + bv.z, 0.f)) |
                  ((unsigned int)f2bf(fmaxf(d.w + bv.w, 0.f)) << 16);
            *reinterpret_cast<uint2*>(&bufB[((o0 >> 3)*PDIM + p)*8 + (o0 & 7)]) = q;
        }
    }
    __syncthreads();

    // ---- L3 (256 -> 256): read bufB, write bufA ----
    f32x4 acc3[2][8];
    #pragma unroll
    for (int a = 0; a < 2; ++a)
        #pragma unroll
        for (int p = 0; p < 8; ++p) acc3[a][p] = (f32x4)0.f;
    for (int ks = 0; ks < 8; ++ks) {
        bf16x8 a0 = w3f[((2*w  )*8 + ks)*64 + lane];
        bf16x8 a1 = w3f[((2*w+1)*8 + ks)*64 + lane];
        __builtin_amdgcn_s_setprio(1);
        #pragma unroll
        for (int pt = 0; pt < 8; ++pt) {
            bf16x8 b = pB[(ks*4 + kg)*PDIM + pt*16 + lp];
            acc3[0][pt] = __builtin_amdgcn_mfma_f32_16x16x32_bf16(a0, b, acc3[0][pt], 0, 0, 0);
            acc3[1][pt] = __builtin_amdgcn_mfma_f32_16x16x32_bf16(a1, b, acc3[1][pt], 0, 0, 0);
        }
        __builtin_amdgcn_s_setprio(0);
    }
    #pragma unroll
    for (int a = 0; a < 2; ++a) {
        int ot = 2*w + a;
        float4 bv = *reinterpret_cast<const float4*>(b3 + ot*16 + kg*4);
        int o0 = ot*16 + kg*4;
        #pragma unroll
        for (int pt = 0; pt < 8; ++pt) {
            f32x4 d = acc3[a][pt];
            int p = pt*16 + lp;
            uint2 q;
            q.x = (unsigned int)f2bf(fmaxf(d.x + bv.x, 0.f)) |
                  ((unsigned int)f2bf(fmaxf(d.y + bv.y, 0.f)) << 16);
            q.y = (unsigned int)f2bf(fmaxf(d.z + bv.z, 0.f)) |
                  ((unsigned int)f2bf(fmaxf(d.w + bv.w, 0.f)) << 16);
            *reinterpret_cast<uint2*>(&bufA[((o0 >> 3)*PDIM + p)*8 + (o0 & 7)]) = q;
        }
    }
    __syncthreads();

    // ---- L4 (256 -> 128): read bufA, write bufB. wave w owns o-tile w. ----
    f32x4 acc4[8];
    #pragma unroll
    for (int p = 0; p < 8; ++p) acc4[p] = (f32x4)0.f;
    for (int ks = 0; ks < 8; ++ks) {
        bf16x8 a0 = w4f[(w*8 + ks)*64 + lane];
        __builtin_amdgcn_s_setprio(1);
        #pragma unroll
        for (int pt = 0; pt < 8; ++pt) {
            bf16x8 b = pA[(ks*4 + kg)*PDIM + pt*16 + lp];
            acc4[pt] = __builtin_amdgcn_mfma_f32_16x16x32_bf16(a0, b, acc4[pt], 0, 0, 0);
        }
        __builtin_amdgcn_s_setprio(0);
    }
    {
        int ot = w;
        float4 bv = *reinterpret_cast<const float4*>(b4 + ot*16 + kg*4);
        int o0 = ot*16 + kg*4;
        #pragma unroll
        for (int pt = 0; pt < 8; ++pt) {
            f32x4 d = acc4[pt];
            int p = pt*16 + lp;
            uint2 q;
            q.x = (unsigned int)f2bf(fmaxf(d.x + bv.x, 0.f)) |
                  ((unsigned int)f2bf(fmaxf(d.y + bv.y, 0.f)) << 16);
            q.y = (unsigned int)f2bf(fmaxf(d.z + bv.z, 0.f)) |
                  ((unsigned int)f2bf(fmaxf(d.w + bv.w, 0.f)) << 16);
            *reinterpret_cast<uint2*>(&bufB[((o0 >> 3)*PDIM + p)*8 + (o0 & 7)]) = q;
        }
    }
    __syncthreads();

    // ---- heads: wave w handles p-tile w (16 cols of 128) via MFMA ----
    f32x4 acch = (f32x4)0.f;
    for (int ks = 0; ks < 4; ++ks) {
        bf16x8 a0 = hpf[ks*64 + lane];
        bf16x8 b  = pB[(ks*4 + kg)*PDIM + w*16 + lp];
        acch = __builtin_amdgcn_mfma_f32_16x16x32_bf16(a0, b, acch, 0, 0, 0);
    }
    // s1-dots: waves 0,1 compute row w's 10 dots (after their head MFMA)
    if (w < 2) {
        float part[10];
        #pragma unroll
        for (int c = 0; c < 10; ++c) part[c] = 0.f;
        const float* sf = s1 + (bn0 + w) * 256;
        #pragma unroll
        for (int t = 0; t < 4; ++t) {
            int k = lane + t*64;
            float sv = sf[k];
            #pragma unroll
            for (int c = 0; c < 8; ++c) part[c] = fmaf(regw[c*384 + k], sv, part[c]);
            part[8] = fmaf(clsw[k],       sv, part[8]);
            part[9] = fmaf(clsw[384 + k], sv, part[9]);
        }
        #pragma unroll
        for (int c = 0; c < 10; ++c) {
            float v = part[c];
            #pragma unroll
            for (int o2 = 1; o2 < 64; o2 <<= 1) v += __shfl_xor(v, o2, 64);
            if (lane == 0) sdot[w][c] = v;
        }
    }
    __syncthreads();

    // ---- dc contraction: wave w covers row w>>2, slots (w&3)*16+lp ----
    {
        int rr = w >> 2;
        int p  = (w & 3)*16 + lp;          // slot within row, 0..63
        #pragma unroll
        for (int r4 = 0; r4 < 4; ++r4) {
            int c = kg*4 + r4;
            float v = 0.f;
            if (c < 10) {
                float hdot = acch[r4] + sdot[rr][c];
                float dw, hb;
                if (c < 8) { dw = dcrw[c*64 + p];     hb = regb[c];   }
                else       { dw = dccw[(c-8)*64 + p]; hb = clsb[c-8]; }
                v = (hdot + hb) * dw;
            }
            #pragma unroll
            for (int o2 = 1; o2 < 16; o2 <<= 1) v += __shfl_xor(v, o2, 64);
            if (lp == 0) pdc[w][c] = v;
        }
    }
    __syncthreads();
    if (tid < 32) {
        int c = tid & 15, rr = tid >> 4;
        if (c < 10) {
            float s = pdc[rr*4+0][c] + pdc[rr*4+1][c] + pdc[rr*4+2][c] + pdc[rr*4+3][c];
            int bn = bn0 + rr;
            if (c < 8) outp[2048 + bn*8 + c] = s + dcrb[c];
            else       outp[bn*2 + (c-8)]    = s + dccb[c-8];
        }
    }
}

extern "C" void kernel_launch(void* const* d_in, const int* in_sizes, int n_in,
                              void* d_out, int out_size, void* d_ws, size_t ws_size,
                              hipStream_t stream)
{
    const float* grasp = (const float*)d_in[0];
    const float* pc    = (const float*)d_in[1];
    const float* s1    = (const float*)d_in[3];
    const float* W1 = (const float*)d_in[4];  const float* b1 = (const float*)d_in[5];
    const float* W2 = (const float*)d_in[6];  const float* b2 = (const float*)d_in[7];
    const float* W3 = (const float*)d_in[8];  const float* b3 = (const float*)d_in[9];
    const float* W4 = (const float*)d_in[10]; const float* b4 = (const float*)d_in[11];
    const float* regw = (const float*)d_in[12]; const float* regb = (const float*)d_in[13];
    const float* clsw = (const float*)d_in[14]; const float* clsb = (const float*)d_in[15];
    const float* dcrw = (const float*)d_in[16]; const float* dcrb = (const float*)d_in[17];
    const float* dccw = (const float*)d_in[18]; const float* dccb = (const float*)d_in[19];
    float* outp = (float*)d_out;
    // out layout: x_cls [0,2048) | x_reg [2048,10240) | mask [10240,11264)

    char* ws = (char*)d_ws;
    unsigned short* W2p = (unsigned short*)ws;                // 262144 B
    unsigned short* W3p = (unsigned short*)(ws + 262144);     // 131072 B
    unsigned short* W4p = (unsigned short*)(ws + 393216);     //  65536 B
    unsigned short* Hp  = (unsigned short*)(ws + 458752);     //   4096 B
    unsigned short* W1p = (unsigned short*)(ws + 462848);     //  32768 B
    float4*        xyzw = (float4*)       (ws + 495616);      // 640000 B

    k_pack<<<453, 256, 0, stream>>>(W1, b1, W2, W3, W4, regw, clsw, pc,
                                    W2p, W3p, W4p, Hp, W1p, xyzw);
    k_fused<<<512, 512, 0, stream>>>(grasp, xyzw, s1, b2, b3, b4,
                                     W2p, W3p, W4p, Hp, W1p,
                                     regw, regb, clsw, clsb, dcrw, dcrb, dccw, dccb,
                                     outp);
}

// Round 8
// 181.083 us; speedup vs baseline: 1.1663x; 1.1663x over previous
//
#include <hip/hip_runtime.h>
#include <hip/hip_bf16.h>

// PointNet2Refine: [K0] pack weights + xyzw table -> [Km] dense ball-query
// mask table -> [K1] fused scan/transform + MFMA MLP (round-5 structure).
// B=2, NUM=512, A=20000, Bn=1024.

#define A_PTS   20000
#define BN_TOT  1024
#define NNEI    192
#define GNUM    64
#define R2      0.09f
#define CHUNKS  313   // ceil(20000/64)

typedef __attribute__((ext_vector_type(8))) short bf16x8;
typedef __attribute__((ext_vector_type(4))) float f32x4;

__device__ inline unsigned short f2bf(float v) {
    __hip_bfloat16 h = __float2bfloat16(v);
    return *reinterpret_cast<unsigned short*>(&h);
}

// ---------------- K0: pack weights (coalesced) + xyzw table -----------------
// 16x16 frag contract (round-5, proven):
//   dst[((ot*KS+ks)*64+l)*8+e] = W[ot*16+(l&15)][ks*32+(l>>4)*8+e]
// Same k-map used on the LDS B-read side, so any k-map error cancels.
#define P_W2_END 32768            // 256 o * 128 k4
#define P_W3_END 49152            // + 256 o * 64 k4
#define P_W4_END 57344            // + 128 o * 64 k4
#define P_HP_END 59392            // + 2048 elementwise
#define P_W1_END 75776            // + 32 ot * 512 elementwise (W1 + b1 at k=3)
#define P_XW_END 115776           // + 40000 points
__global__ __launch_bounds__(256) void k_pack(
    const float* __restrict__ W1, const float* __restrict__ b1,
    const float* __restrict__ W2, const float* __restrict__ W3,
    const float* __restrict__ W4,
    const float* __restrict__ regw, const float* __restrict__ clsw,
    const float* __restrict__ pc,
    unsigned short* __restrict__ W2p, unsigned short* __restrict__ W3p,
    unsigned short* __restrict__ W4p, unsigned short* __restrict__ Hp,
    unsigned short* __restrict__ W1p, float4* __restrict__ xyzw)
{
    int t = blockIdx.x * 256 + threadIdx.x;
    if (t < P_W2_END) {
        int o = t >> 7, k = (t & 127) << 2;          // o in [0,256), k in [0,512)
        float4 v = *reinterpret_cast<const float4*>(W2 + o*512 + k);
        int ot=o>>4, lp=o&15, ks=k>>5, kg=(k>>3)&3, e0=k&7;
        int d = ((ot*16 + ks)*64 + kg*16 + lp)*8 + e0;
        *reinterpret_cast<ushort4*>(W2p + d) =
            make_ushort4(f2bf(v.x), f2bf(v.y), f2bf(v.z), f2bf(v.w));
    } else if (t < P_W3_END) {
        int i = t - P_W2_END;
        int o = i >> 6, k = (i & 63) << 2;           // o in [0,256), k in [0,256)
        float4 v = *reinterpret_cast<const float4*>(W3 + o*256 + k);
        int ot=o>>4, lp=o&15, ks=k>>5, kg=(k>>3)&3, e0=k&7;
        int d = ((ot*8 + ks)*64 + kg*16 + lp)*8 + e0;
        *reinterpret_cast<ushort4*>(W3p + d) =
            make_ushort4(f2bf(v.x), f2bf(v.y), f2bf(v.z), f2bf(v.w));
    } else if (t < P_W4_END) {
        int i = t - P_W3_END;
        int o = i >> 6, k = (i & 63) << 2;           // o in [0,128), k in [0,256)
        float4 v = *reinterpret_cast<const float4*>(W4 + o*256 + k);
        int ot=o>>4, lp=o&15, ks=k>>5, kg=(k>>3)&3, e0=k&7;
        int d = ((ot*8 + ks)*64 + kg*16 + lp)*8 + e0;
        *reinterpret_cast<ushort4*>(W4p + d) =
            make_ushort4(f2bf(v.x), f2bf(v.y), f2bf(v.z), f2bf(v.w));
    } else if (t < P_HP_END) {
        int i2 = t - P_W4_END;
        int ks = i2 >> 9, r = i2 & 511, l = r >> 3, e = r & 7;
        int c = l & 15;
        int k = 256 + ks*32 + ((l >> 4) << 3) + e;
        float v = 0.f;
        if (c < 8)       v = regw[c*384 + k];
        else if (c < 10) v = clsw[(c-8)*384 + k];
        Hp[i2] = f2bf(v);
    } else if (t < P_W1_END) {
        int i = t - P_HP_END;
        int ot = i >> 9, r = i & 511, l = r >> 3, e = r & 7;
        int o = ot*16 + (l & 15);
        int k = ((l >> 4) << 3) + e;
        float v = (k < 3) ? W1[o*3 + k] : (k == 3 ? b1[o] : 0.f);
        W1p[i] = f2bf(v);
    } else if (t < P_XW_END) {
        int i = t - P_W1_END;
        int b = (i >= A_PTS) ? 1 : 0;
        int a = i - b * A_PTS;
        const float* pp = pc + b*(A_PTS*6) + a*6;
        float x = pp[0], y = pp[1], z = pp[2];
        xyzw[i] = make_float4(x, y, z, x*x + y*y + z*z);
    }
}

// ---------------- Km: dense ball-query mask table ---------------------------
// Block = (batch b, 4-chunk point group pg, 128-center group cg).
// Thread owns one point (in registers); 128 centers staged in LDS; one
// ballot per (center, chunk). masks_g[bn*CHUNKS + chunk] = 64-bit mask.
// Same fp32 formula / same xyzw values as round-5's in-block phase B.
__global__ __launch_bounds__(256) void k_mask(
    const float* __restrict__ grasp, const float4* __restrict__ xyzw,
    unsigned long long* __restrict__ masks_g)
{
    __shared__ float4 cen[128];
    int bid = blockIdx.x;
    int b   = bid / 316;            // 79 pg * 4 cg
    int rem = bid % 316;
    int pg  = rem >> 2, cg = rem & 3;
    int tid = threadIdx.x;

    if (tid < 128) {
        int m = cg*128 + tid;
        const float* g = grasp + (b*512 + m)*8;
        float cx = g[0], cy = g[1], cz = g[2];
        cen[tid] = make_float4(cx, cy, cz, cx*cx + cy*cy + cz*cz);
    }
    __syncthreads();

    int a = pg*256 + tid;
    float4 q = (a < A_PTS) ? xyzw[b*A_PTS + a]
                           : make_float4(0.f, 0.f, 0.f, 1e30f);
    int chunk = pg*4 + (tid >> 6);
    bool wr = ((tid & 63) == 0) && (chunk < CHUNKS);
    unsigned long long* mb_base = masks_g + (size_t)(b*512)*CHUNKS + chunk;

    for (int i = 0; i < 128; ++i) {
        float4 cn = cen[i];
        float d = cn.w + q.w - 2.0f*(cn.x*q.x + cn.y*q.y + cn.z*q.z);
        unsigned long long mb = __ballot(d < R2);
        if (wr) mb_base[(size_t)(cg*128 + i)*CHUNKS] = mb;
    }
}

// ---------------- K1: fused scan + transform + MLP + heads ------------------
// One block = one bn row. 512 thr = 8 waves. Round-5 structure (proven 89us);
// phase B now just loads the precomputed mask row (2.5 KB) and scans.
__global__ __launch_bounds__(512, 4) void k_fused(
    const float* __restrict__ grasp, const float4* __restrict__ xyzw,
    const unsigned long long* __restrict__ masks_g,
    const float* __restrict__ s1,
    const float* __restrict__ b2, const float* __restrict__ b3,
    const float* __restrict__ b4,
    const unsigned short* __restrict__ W2p, const unsigned short* __restrict__ W3p,
    const unsigned short* __restrict__ W4p, const unsigned short* __restrict__ Hp,
    const unsigned short* __restrict__ W1p,
    const float* __restrict__ regw, const float* __restrict__ regb,
    const float* __restrict__ clsw, const float* __restrict__ clsb,
    const float* __restrict__ dcrw, const float* __restrict__ dcrb,
    const float* __restrict__ dccw, const float* __restrict__ dccb,
    float* __restrict__ outp)
{
    __shared__ __align__(16) unsigned short bufA[32*64*8];   // 32 KiB
    __shared__ __align__(16) unsigned short bufB[32*64*8];   // 32 KiB
    __shared__ float sdot[16];
    __shared__ float pdc[4][16];
    __shared__ unsigned long long masks[CHUNKS];
    __shared__ int soff[CHUNKS];
    __shared__ int idx_sh[NNEI];
    __shared__ float4 tval[NNEI];
    __shared__ float4 gp[GNUM];
    __shared__ unsigned long long tmask[3];
    __shared__ int sh_total, sh_pad;

    int bn   = blockIdx.x;
    int tid  = threadIdx.x;
    int lane = tid & 63;
    int w    = tid >> 6;      // 0..7

    const float* g = grasp + bn * 8;
    float g0=g[0], g1=g[1], g2=g[2], g3=g[3], g4=g[4], g5=g[5], g6=g[6], g7=g[7];
    float cx=g0, cy=g1, cz=g2;
    const float4* xw = xyzw + (bn >> 9) * A_PTS;

    // ================= Phase B: load mask row + ordered scan ===============
    {
        const unsigned long long* mrow = masks_g + (size_t)bn * CHUNKS;
        if (tid < CHUNKS) masks[tid] = mrow[tid];
    }
    __syncthreads();

    if (w == 0) {   // ordered prefix scan of chunk popcounts
        int c0 = lane * 5;
        int cnts[5]; int s = 0;
        #pragma unroll
        for (int i = 0; i < 5; ++i) {
            int c = c0 + i;
            int v = (c < CHUNKS) ? __popcll(masks[c]) : 0;
            cnts[i] = v; s += v;
        }
        int incl = s;
        for (int o2 = 1; o2 < 64; o2 <<= 1) {
            int v = __shfl_up(incl, o2, 64);
            if (lane >= o2) incl += v;
        }
        int run = incl - s;
        #pragma unroll
        for (int i = 0; i < 5; ++i) {
            int c = c0 + i;
            if (c < CHUNKS) soff[c] = run;
            run += cnts[i];
        }
        int total = __shfl(incl, 63, 64);
        int fc = 0x7fffffff;
        #pragma unroll
        for (int i = 0; i < 5; ++i) {
            int c = c0 + i;
            if (c < CHUNKS && masks[c] != 0ull) { fc = c; break; }
        }
        for (int o2 = 32; o2 >= 1; o2 >>= 1) fc = min(fc, __shfl_xor(fc, o2, 64));
        if (lane == 0) {
            sh_total = total;
            sh_pad = (fc == 0x7fffffff) ? 0
                     : fc * 64 + (int)__builtin_ctzll(masks[fc]);
        }
    }
    __syncthreads();

    int total = sh_total, padval = sh_pad;
    for (int c = w; c < CHUNKS; c += 8) {
        unsigned long long mb = masks[c];
        int base = soff[c];
        if (mb != 0ull && base < NNEI && ((mb >> lane) & 1ull)) {
            int pos = base + __popcll(mb & ((1ull << lane) - 1ull));
            if (pos < NNEI) idx_sh[pos] = c * 64 + lane;
        }
    }
    int cnt = total < NNEI ? total : NNEI;
    for (int p = cnt + tid; p < NNEI; p += 512) idx_sh[p] = padval;
    __syncthreads();

    // ================= Phase T: gripper transform =================
    float gsum = g0+g1+g2+g3+g4+g5+g6+g7;
    bool gmask = (gsum != -8.0f);
    float ay0=g3, ay1=g4, ay2=g5;
    float cth = cosf(g6), sth = sinf(g6);
    float ny = sqrtf(ay0*ay0 + ay1*ay1 + ay2*ay2) + 1e-12f;
    ay0/=ny; ay1/=ny; ay2/=ny;
    float ax0=ay1, ax1=-ay0;
    float nx = sqrtf(ax0*ax0 + ax1*ax1) + 1e-12f;
    ax0/=nx; ax1/=nx;
    float az0 =  ax1*ay2;
    float az1 = -ax0*ay2;
    float az2 =  ax0*ay1 - ax1*ay0;
    float nz = sqrtf(az0*az0 + az1*az1 + az2*az2);
    if (nz == 0.0f) { az0=0.f; az1=0.f; az2=1.f; }
    else            { az0/=nz; az1/=nz; az2/=nz; }
    float ap0 = ax0*cth + az0*sth;
    float ap1 = ax1*cth + az1*sth;
    float ap2 =           az2*sth;
    float na = sqrtf(ap0*ap0 + ap1*ap1 + ap2*ap2) + 1e-12f;
    ap0/=na; ap1/=na; ap2/=na;
    float mi0 = ap1*ay2 - ap2*ay1;
    float mi1 = ap2*ay0 - ap0*ay2;
    float mi2 = ap0*ay1 - ap1*ay0;

    bool inside = false;
    if (tid < NNEI) {
        float4 Q = xw[idx_sh[tid]];
        float qx = Q.x-cx, qy = Q.y-cy, qz = Q.z-cz;
        float tx = ap0*qx + ap1*qy + ap2*qz;
        float ty = ay0*qx + ay1*qy + ay2*qz;
        float tz = mi0*qx + mi1*qy + mi2*qz;
        inside = (tx > 0.f) && (tx < 0.3f) && (ty > -0.15f) && (ty < 0.15f)
              && (tz > -0.1f) && (tz < 0.1f);
        tval[tid] = make_float4(tx, ty, tz, 0.f);
    }
    unsigned long long mb = __ballot(inside);
    if (lane == 0 && w < 3) tmask[w] = mb;
    __syncthreads();

    unsigned long long m0 = tmask[0], m1 = tmask[1], m2 = tmask[2];
    int c0 = __popcll(m0), c1 = __popcll(m1), c2 = __popcll(m2);
    int tfound = c0 + c1 + c2;
    int firstj = 0;
    if (m0)      firstj = (int)__builtin_ctzll(m0);
    else if (m1) firstj = 64 + (int)__builtin_ctzll(m1);
    else if (m2) firstj = 128 + (int)__builtin_ctzll(m2);
    float4 padv = tval[firstj];

    if (tid < NNEI && inside) {
        int wbase = (w == 0) ? 0 : (w == 1 ? c0 : c0 + c1);
        int rank = wbase + __popcll(mb & ((1ull << lane) - 1ull));
        if (rank < GNUM) gp[rank] = tval[tid];
    }
    int gcnt = tfound < GNUM ? tfound : GNUM;
    for (int p = gcnt + tid; p < GNUM; p += 512) gp[p] = padv;
    if (tid == 0)
        outp[10240 + bn] = (total > 0 && tfound > 0 && gmask) ? 1.0f : 0.0f;
    __syncthreads();

    // ================= Phase M: MFMA MLP + heads =================
    int kg = lane >> 4;     // 0..3
    int lp = lane & 15;

    const bf16x8* pA  = reinterpret_cast<const bf16x8*>(bufA);
    const bf16x8* pB  = reinterpret_cast<const bf16x8*>(bufB);
    const bf16x8* w1f = reinterpret_cast<const bf16x8*>(W1p);
    const bf16x8* w2f = reinterpret_cast<const bf16x8*>(W2p);
    const bf16x8* w3f = reinterpret_cast<const bf16x8*>(W3p);
    const bf16x8* w4f = reinterpret_cast<const bf16x8*>(W4p);
    const bf16x8* hpf = reinterpret_cast<const bf16x8*>(Hp);

    // B-frag for L1 (16x16): coords at assumed-k {0,1,2}, 1.0 at k=3 (bias).
    bf16x8 bfr[4];
    #pragma unroll
    for (int pt = 0; pt < 4; ++pt) {
        float4 Pp = gp[pt*16 + lp];
        bf16x8 b = (bf16x8)(short)0;
        if (kg == 0) {
            b[0] = (short)f2bf(Pp.x);
            b[1] = (short)f2bf(Pp.y);
            b[2] = (short)f2bf(Pp.z);
            b[3] = (short)0x3F80;      // bf16(1.0)
        }
        bfr[pt] = b;
    }

    // ---- L1 (16x16, K-padded 3+bias) + L2 (K=512 in two 256 halves) ----
    f32x4 acc2[2][4];
    #pragma unroll
    for (int a = 0; a < 2; ++a)
        #pragma unroll
        for (int p = 0; p < 4; ++p) acc2[a][p] = (f32x4)0.f;

    for (int h = 0; h < 2; ++h) {
        __syncthreads();
        // L1: wave w computes global o-tiles(16) h*16 + {2w, 2w+1}
        f32x4 accL[2][4];
        #pragma unroll
        for (int a = 0; a < 2; ++a)
            #pragma unroll
            for (int p = 0; p < 4; ++p) accL[a][p] = (f32x4)0.f;
        {
            bf16x8 a0 = w1f[(h*16 + 2*w    )*64 + lane];
            bf16x8 a1 = w1f[(h*16 + 2*w + 1)*64 + lane];
            __builtin_amdgcn_s_setprio(1);
            #pragma unroll
            for (int pt = 0; pt < 4; ++pt) {
                accL[0][pt] = __builtin_amdgcn_mfma_f32_16x16x32_bf16(a0, bfr[pt], accL[0][pt], 0, 0, 0);
                accL[1][pt] = __builtin_amdgcn_mfma_f32_16x16x32_bf16(a1, bfr[pt], accL[1][pt], 0, 0, 0);
            }
            __builtin_amdgcn_s_setprio(0);
        }
        // L1 epilogue: relu -> bufA (local channels (2w+a)*16 + kg*4 .. +3)
        #pragma unroll
        for (int a = 0; a < 2; ++a) {
            int o0 = (2*w + a)*16 + kg*4;
            #pragma unroll
            for (int pt = 0; pt < 4; ++pt) {
                f32x4 d = accL[a][pt];
                int p = pt*16 + lp;
                uint2 q;
                q.x = (unsigned int)f2bf(fmaxf(d.x, 0.f)) |
                      ((unsigned int)f2bf(fmaxf(d.y, 0.f)) << 16);
                q.y = (unsigned int)f2bf(fmaxf(d.z, 0.f)) |
                      ((unsigned int)f2bf(fmaxf(d.w, 0.f)) << 16);
                *reinterpret_cast<uint2*>(&bufA[((o0 >> 3)*64 + p)*8 + (o0 & 7)]) = q;
            }
        }
        __syncthreads();
        // L2 accumulate over this half's 256 k-channels
        for (int ks = 0; ks < 8; ++ks) {
            int ksg = h*8 + ks;
            bf16x8 a0 = w2f[((2*w  )*16 + ksg)*64 + lane];
            bf16x8 a1 = w2f[((2*w+1)*16 + ksg)*64 + lane];
            __builtin_amdgcn_s_setprio(1);
            #pragma unroll
            for (int pt = 0; pt < 4; ++pt) {
                bf16x8 b = pA[(ks*4 + kg)*64 + pt*16 + lp];
                acc2[0][pt] = __builtin_amdgcn_mfma_f32_16x16x32_bf16(a0, b, acc2[0][pt], 0, 0, 0);
                acc2[1][pt] = __builtin_amdgcn_mfma_f32_16x16x32_bf16(a1, b, acc2[1][pt], 0, 0, 0);
            }
            __builtin_amdgcn_s_setprio(0);
        }
    }
    #pragma unroll
    for (int a = 0; a < 2; ++a) {
        int ot = 2*w + a;
        float4 bv = *reinterpret_cast<const float4*>(b2 + ot*16 + kg*4);
        int o0 = ot*16 + kg*4;
        #pragma unroll
        for (int pt = 0; pt < 4; ++pt) {
            f32x4 d = acc2[a][pt];
            int p = pt*16 + lp;
            uint2 q;
            q.x = (unsigned int)f2bf(fmaxf(d.x + bv.x, 0.f)) |
                  ((unsigned int)f2bf(fmaxf(d.y + bv.y, 0.f)) << 16);
            q.y = (unsigned int)f2bf(fmaxf(d.z + bv.z, 0.f)) |
                  ((unsigned int)f2bf(fmaxf(d.w + bv.w, 0.f)) << 16);
            *reinterpret_cast<uint2*>(&bufB[((o0 >> 3)*64 + p)*8 + (o0 & 7)]) = q;
        }
    }
    __syncthreads();

    // ---- L3 (256 -> 256): read bufB, write bufA ----
    f32x4 acc3[2][4];
    #pragma unroll
    for (int a = 0; a < 2; ++a)
        #pragma unroll
        for (int p = 0; p < 4; ++p) acc3[a][p] = (f32x4)0.f;
    for (int ks = 0; ks < 8; ++ks) {
        bf16x8 a0 = w3f[((2*w  )*8 + ks)*64 + lane];
        bf16x8 a1 = w3f[((2*w+1)*8 + ks)*64 + lane];
        __builtin_amdgcn_s_setprio(1);
        #pragma unroll
        for (int pt = 0; pt < 4; ++pt) {
            bf16x8 b = pB[(ks*4 + kg)*64 + pt*16 + lp];
            acc3[0][pt] = __builtin_amdgcn_mfma_f32_16x16x32_bf16(a0, b, acc3[0][pt], 0, 0, 0);
            acc3[1][pt] = __builtin_amdgcn_mfma_f32_16x16x32_bf16(a1, b, acc3[1][pt], 0, 0, 0);
        }
        __builtin_amdgcn_s_setprio(0);
    }
    #pragma unroll
    for (int a = 0; a < 2; ++a) {
        int ot = 2*w + a;
        float4 bv = *reinterpret_cast<const float4*>(b3 + ot*16 + kg*4);
        int o0 = ot*16 + kg*4;
        #pragma unroll
        for (int pt = 0; pt < 4; ++pt) {
            f32x4 d = acc3[a][pt];
            int p = pt*16 + lp;
            uint2 q;
            q.x = (unsigned int)f2bf(fmaxf(d.x + bv.x, 0.f)) |
                  ((unsigned int)f2bf(fmaxf(d.y + bv.y, 0.f)) << 16);
            q.y = (unsigned int)f2bf(fmaxf(d.z + bv.z, 0.f)) |
                  ((unsigned int)f2bf(fmaxf(d.w + bv.w, 0.f)) << 16);
            *reinterpret_cast<uint2*>(&bufA[((o0 >> 3)*64 + p)*8 + (o0 & 7)]) = q;
        }
    }
    __syncthreads();

    // ---- L4 (256 -> 128): read bufA, write bufB. wave w owns o-tile w. ----
    f32x4 acc4[4];
    #pragma unroll
    for (int p = 0; p < 4; ++p) acc4[p] = (f32x4)0.f;
    for (int ks = 0; ks < 8; ++ks) {
        bf16x8 a0 = w4f[(w*8 + ks)*64 + lane];
        __builtin_amdgcn_s_setprio(1);
        #pragma unroll
        for (int pt = 0; pt < 4; ++pt) {
            bf16x8 b = pA[(ks*4 + kg)*64 + pt*16 + lp];
            acc4[pt] = __builtin_amdgcn_mfma_f32_16x16x32_bf16(a0, b, acc4[pt], 0, 0, 0);
        }
        __builtin_amdgcn_s_setprio(0);
    }
    {
        int ot = w;
        float4 bv = *reinterpret_cast<const float4*>(b4 + ot*16 + kg*4);
        int o0 = ot*16 + kg*4;
        #pragma unroll
        for (int pt = 0; pt < 4; ++pt) {
            f32x4 d = acc4[pt];
            int p = pt*16 + lp;
            uint2 q;
            q.x = (unsigned int)f2bf(fmaxf(d.x + bv.x, 0.f)) |
                  ((unsigned int)f2bf(fmaxf(d.y + bv.y, 0.f)) << 16);
            q.y = (unsigned int)f2bf(fmaxf(d.z + bv.z, 0.f)) |
                  ((unsigned int)f2bf(fmaxf(d.w + bv.w, 0.f)) << 16);
            *reinterpret_cast<uint2*>(&bufB[((o0 >> 3)*64 + p)*8 + (o0 & 7)]) = q;
        }
    }
    __syncthreads();

    // ---- heads: MFMA on h4 (waves 0-3, pt=w), s1-dot fp32 (wave 4) ----
    f32x4 acch = (f32x4)0.f;
    if (w < 4) {
        for (int ks = 0; ks < 4; ++ks) {
            bf16x8 a0 = hpf[ks*64 + lane];
            bf16x8 b  = pB[(ks*4 + kg)*64 + w*16 + lp];
            acch = __builtin_amdgcn_mfma_f32_16x16x32_bf16(a0, b, acch, 0, 0, 0);
        }
    } else if (w == 4) {
        float part[10];
        #pragma unroll
        for (int c = 0; c < 10; ++c) part[c] = 0.f;
        const float* sf = s1 + bn * 256;
        #pragma unroll
        for (int t = 0; t < 4; ++t) {
            int k = lane + t*64;
            float sv = sf[k];
            #pragma unroll
            for (int c = 0; c < 8; ++c) part[c] = fmaf(regw[c*384 + k], sv, part[c]);
            part[8] = fmaf(clsw[k],       sv, part[8]);
            part[9] = fmaf(clsw[384 + k], sv, part[9]);
        }
        #pragma unroll
        for (int c = 0; c < 10; ++c) {
            float v = part[c];
            #pragma unroll
            for (int o2 = 1; o2 < 64; o2 <<= 1) v += __shfl_xor(v, o2, 64);
            if (lane == 0) sdot[c] = v;
        }
    }
    __syncthreads();

    // ---- dc contraction over the 64 slots ----
    if (w < 4) {
        int p = w*16 + lp;
        #pragma unroll
        for (int r = 0; r < 4; ++r) {
            int c = kg*4 + r;
            float v = 0.f;
            if (c < 10) {
                float hdot = acch[r] + sdot[c];
                float dw, hb;
                if (c < 8) { dw = dcrw[c*64 + p];     hb = regb[c];   }
                else       { dw = dccw[(c-8)*64 + p]; hb = clsb[c-8]; }
                v = (hdot + hb) * dw;
            }
            #pragma unroll
            for (int o2 = 1; o2 < 16; o2 <<= 1) v += __shfl_xor(v, o2, 64);
            if (lp == 0) pdc[w][c] = v;
        }
    }
    __syncthreads();
    if (tid < 16) {
        int c = tid;
        if (c < 10) {
            float s = pdc[0][c] + pdc[1][c] + pdc[2][c] + pdc[3][c];
            if (c < 8) outp[2048 + bn*8 + c] = s + dcrb[c];
            else       outp[bn*2 + (c-8)]    = s + dccb[c-8];
        }
    }
}

extern "C" void kernel_launch(void* const* d_in, const int* in_sizes, int n_in,
                              void* d_out, int out_size, void* d_ws, size_t ws_size,
                              hipStream_t stream)
{
    const float* grasp = (const float*)d_in[0];
    const float* pc    = (const float*)d_in[1];
    const float* s1    = (const float*)d_in[3];
    const float* W1 = (const float*)d_in[4];  const float* b1 = (const float*)d_in[5];
    const float* W2 = (const float*)d_in[6];  const float* b2 = (const float*)d_in[7];
    const float* W3 = (const float*)d_in[8];  const float* b3 = (const float*)d_in[9];
    const float* W4 = (const float*)d_in[10]; const float* b4 = (const float*)d_in[11];
    const float* regw = (const float*)d_in[12]; const float* regb = (const float*)d_in[13];
    const float* clsw = (const float*)d_in[14]; const float* clsb = (const float*)d_in[15];
    const float* dcrw = (const float*)d_in[16]; const float* dcrb = (const float*)d_in[17];
    const float* dccw = (const float*)d_in[18]; const float* dccb = (const float*)d_in[19];
    float* outp = (float*)d_out;
    // out layout: x_cls [0,2048) | x_reg [2048,10240) | mask [10240,11264)

    char* ws = (char*)d_ws;
    unsigned short* W2p = (unsigned short*)ws;                // 262144 B
    unsigned short* W3p = (unsigned short*)(ws + 262144);     // 131072 B
    unsigned short* W4p = (unsigned short*)(ws + 393216);     //  65536 B
    unsigned short* Hp  = (unsigned short*)(ws + 458752);     //   4096 B
    unsigned short* W1p = (unsigned short*)(ws + 462848);     //  32768 B
    float4*        xyzw = (float4*)       (ws + 495616);      // 640000 B
    unsigned long long* masks_g =
        (unsigned long long*)(ws + 1135616);                  // 1024*313*8 = 2564096 B

    k_pack<<<453, 256, 0, stream>>>(W1, b1, W2, W3, W4, regw, clsw, pc,
                                    W2p, W3p, W4p, Hp, W1p, xyzw);
    k_mask<<<632, 256, 0, stream>>>(grasp, xyzw, masks_g);
    k_fused<<<1024, 512, 0, stream>>>(grasp, xyzw, masks_g, s1, b2, b3, b4,
                                      W2p, W3p, W4p, Hp, W1p,
                                      regw, regb, clsw, clsb, dcrw, dcrb, dccw, dccb,
                                      outp);
}